// Round 7
// baseline (149.449 us; speedup 1.0000x reference)
//
#include <hip/hip_runtime.h>
#include <hip/hip_bf16.h>

// SelfAttentionLayer: B=64, N=1024, C=128, D=64
// R11 == R10 resubmitted verbatim (R10's bench died to "MI355X container
// failed twice" — infra, not kernel; line audit found no defects).
// Single fused kernel, NO cross-block dependencies (fixes R6's fatal
// cross-XCD visibility problem by never sharing K/V between blocks).
// Block (b,qh) = 4 waves x 32 q rows:
//   Phase Q: project own 128 q rows (hi/lo compensated MFMA, port of qkv),
//            store q*SC bf16 to LDS Qs.
//   kt loop (16 x 64-key tiles): stage x[kt] hi-frags to LDS -> project
//            K,V tiles via MFMA (32/wave) -> scatter K/V into the exact
//            R4 frag layouts (now in LDS) -> R9 attn body (QK, exp->Pl,
//            PV) -> 3 syncs/kt.
// Deletes: qkv kernel (~45us), K/V/qs global round-trip (48 MB L2+HBM),
// one launch gap. Adds: 8x-redundant K/V proj MFMA (+17 GF ~ +7us) and
// 8x x re-read (XCD-affine: blockIdx%8 == b%8, slice set fits L2).
// All frag layouts/index math verbatim from verified R4/R9 kernels.
// LDS: Xs 16K + KVb 16K + Qs 18K + Pl 18K = 68 KB -> 2 blocks/CU.

#define Bsz 64
#define Nsz 1024
#define Csz 128
#define Dsz 64

typedef __attribute__((ext_vector_type(8))) short short8;
typedef __attribute__((ext_vector_type(4))) float f32x4;

__device__ __forceinline__ unsigned short f2bf(float f) {
    union { float f; unsigned u; } v; v.f = f;
    unsigned r = v.u + 0x7FFF + ((v.u >> 16) & 1);
    return (unsigned short)(r >> 16);
}
__device__ __forceinline__ float bf2f(unsigned short h) {
    union { unsigned u; float f; } v; v.u = ((unsigned)h) << 16;
    return v.f;
}
__device__ __forceinline__ unsigned pack_bf16rn(float lo, float hi) {
    unsigned ulo = __float_as_uint(lo) + 0x8000u;
    unsigned uhi = __float_as_uint(hi) + 0x8000u;
    return __builtin_amdgcn_perm(uhi, ulo, 0x07060302u);
}

#define SCq (0.125f * 1.44269504f)     // 1/sqrt(D) * log2(e) folded into q
#define INV_SC (1.0f / (0.125f * 1.44269504f))

// ---------------- Kernel 0: weight prep -> B-frag layout bf16 ----------------
__global__ __launch_bounds__(256) void wprep_kernel(
    const float* __restrict__ Wq, const float* __restrict__ Wk,
    const float* __restrict__ Wv, unsigned short* __restrict__ wfrag)
{
    int t = blockIdx.x * 256 + threadIdx.x;   // 0..1023 = (dt,ksi,lane)
    int lane = t & 63, ksi = (t >> 6) & 3, dt = t >> 8;
    int l16 = lane & 15, quad = lane >> 4;
    int d = dt * 16 + l16;
    int c0 = ksi * 32 + quad * 8;
    short8 h8, l8, k8, v8;
    #pragma unroll
    for (int j = 0; j < 8; j++) {
        float w = Wq[(c0 + j) * Dsz + d];
        unsigned short h = f2bf(w);
        h8[j] = (short)h;
        l8[j] = (short)f2bf(w - bf2f(h));
        k8[j] = (short)f2bf(Wk[(c0 + j) * Dsz + d]);
        v8[j] = (short)f2bf(Wv[(c0 + j) * Dsz + d]);
    }
    int idx = (dt * 4 + ksi) * 64 + lane;
    ((short8*)wfrag)[0 * 1024 + idx] = h8;
    ((short8*)wfrag)[1 * 1024 + idx] = l8;
    ((short8*)wfrag)[2 * 1024 + idx] = k8;
    ((short8*)wfrag)[3 * 1024 + idx] = v8;
}

// ---------------- Fused kernel: QKV projection + flash attention ----------------
// grid 512: b = blk&63 (XCD affinity for the shared x slice), qh = blk>>6.
__global__ __launch_bounds__(256, 2) void fused_kernel(
    const float* __restrict__ x, const unsigned short* __restrict__ wfrag,
    const float* __restrict__ bq, const float* __restrict__ bk,
    const float* __restrict__ bv, float* __restrict__ out)
{
    __shared__ short Xs[8192];         // x hi A-frags, 64 rows x 128 c (16 KB)
    __shared__ short KVb[2][4096];     // [0]=K frags / Q-phase x-lo; [1]=V frags
    __shared__ short Qs[128][72];      // q*SC bf16, row-padded (18 KB)
    __shared__ short Pl[4][32][72];    // per-wave P round-trip (18 KB)

    const int t    = threadIdx.x;
    const int lane = t & 63;
    const int l16  = lane & 15;
    const int quad = lane >> 4;
    const int wave = t >> 6;           // == dt for projection
    const int dt   = wave;
    const int b    = blockIdx.x & 63;
    const int qh   = blockIdx.x >> 6;
    const int d    = dt * 16 + l16;

    // weight B-frags (L2-hot wfrag): wq hi/lo for Q phase, wk/wv for kt loop
    short8 wqh[4], wql[4], wkf[4], wvf[4];
    #pragma unroll
    for (int ksi = 0; ksi < 4; ksi++) {
        int idx = (dt * 4 + ksi) * 64 + lane;
        wqh[ksi] = ((const short8*)wfrag)[0 * 1024 + idx];
        wql[ksi] = ((const short8*)wfrag)[1 * 1024 + idx];
        wkf[ksi] = ((const short8*)wfrag)[2 * 1024 + idx];
        wvf[ksi] = ((const short8*)wfrag)[3 * 1024 + idx];
    }
    const float bqd = bq[d], bkd = bk[d], bvd = bv[d];

    // ================= Phase Q: project own 128 q rows into Qs =================
    #pragma unroll 1
    for (int h64 = 0; h64 < 2; h64++) {
        const long rowbase = (long)b * Nsz + qh * 128 + h64 * 64;
        {   // stage x hi -> Xs, lo -> KVb[0] (A-frag layout, port of qkv)
            const int row = t & 63;
            const float* xrow = x + (rowbase + row) * Csz;
            short* xl = &KVb[0][0];
            #pragma unroll
            for (int p = 0; p < 4; p++) {
                int cb = (t >> 6) + p * 4;
                float4 a  = *(const float4*)(xrow + cb * 8);
                float4 b2 = *(const float4*)(xrow + cb * 8 + 4);
                float f[8] = {a.x, a.y, a.z, a.w, b2.x, b2.y, b2.z, b2.w};
                short8 hi, lo;
                #pragma unroll
                for (int i = 0; i < 8; i++) {
                    unsigned short h = f2bf(f[i]);
                    hi[i] = (short)h;
                    lo[i] = (short)f2bf(f[i] - bf2f(h));
                }
                int unit = ((row >> 4) * 4 + (cb >> 2)) * 64 + ((row & 15) | ((cb & 3) << 4));
                *(short8*)&Xs[unit * 8] = hi;
                *(short8*)&xl[unit * 8] = lo;
            }
        }
        __syncthreads();
        f32x4 aqc[4];
        #pragma unroll
        for (int i = 0; i < 4; i++) aqc[i] = (f32x4){0.f, 0.f, 0.f, 0.f};
        #pragma unroll
        for (int ksi = 0; ksi < 4; ksi++) {
            #pragma unroll
            for (int rt = 0; rt < 4; rt++) {
                short8 ah = *(const short8*)&Xs[((rt * 4 + ksi) * 64 + lane) * 8];
                short8 al = *(const short8*)&KVb[0][((rt * 4 + ksi) * 64 + lane) * 8];
                aqc[rt] = __builtin_amdgcn_mfma_f32_16x16x32_bf16(ah, wqh[ksi], aqc[rt], 0, 0, 0);
                aqc[rt] = __builtin_amdgcn_mfma_f32_16x16x32_bf16(al, wqh[ksi], aqc[rt], 0, 0, 0);
                aqc[rt] = __builtin_amdgcn_mfma_f32_16x16x32_bf16(ah, wql[ksi], aqc[rt], 0, 0, 0);
            }
        }
        #pragma unroll
        for (int rt = 0; rt < 4; rt++)
            #pragma unroll
            for (int r = 0; r < 4; r++) {
                float q = fmaxf(aqc[rt][r] + bqd, 0.f);
                Qs[h64 * 64 + rt * 16 + quad * 4 + r][d] = f2bf(q * SCq);
            }
        __syncthreads();
    }

    // Q A-frags from Qs (own 32 rows per wave)
    short8 aq[2][2];
    #pragma unroll
    for (int s = 0; s < 2; s++) {
        aq[s][0] = *(const short8*)&Qs[wave * 32 + s * 16 + l16][quad * 8];
        aq[s][1] = *(const short8*)&Qs[wave * 32 + s * 16 + l16][32 + quad * 8];
    }

    f32x4 O[2][4];
    float lsum[2][4];
    #pragma unroll
    for (int s = 0; s < 2; s++)
        #pragma unroll
        for (int i = 0; i < 4; i++) { O[s][i] = (f32x4){0.f,0.f,0.f,0.f}; lsum[s][i] = 0.f; }

    // K/V scatter constants (verbatim R4 frag math)
    const int half  = dt >> 1;
    const int quadk = ((dt & 1) << 1) | (l16 >> 3);
    const int jk    = l16 & 7;
    const int ckk   = quad >> 1;
    const int quadp = (quad & 1) * 2;

    // ================= kt loop: project K/V tile, then flash step =================
    #pragma unroll 1
    for (int kt = 0; kt < 16; kt++) {
        {   // stage x hi for key rows kt*64..+63
            const long rowbase = (long)b * Nsz + kt * 64;
            const int row = t & 63;
            const float* xrow = x + (rowbase + row) * Csz;
            #pragma unroll
            for (int p = 0; p < 4; p++) {
                int cb = (t >> 6) + p * 4;
                float4 a  = *(const float4*)(xrow + cb * 8);
                float4 b2 = *(const float4*)(xrow + cb * 8 + 4);
                float f[8] = {a.x, a.y, a.z, a.w, b2.x, b2.y, b2.z, b2.w};
                short8 hi;
                #pragma unroll
                for (int i = 0; i < 8; i++) hi[i] = (short)f2bf(f[i]);
                int unit = ((row >> 4) * 4 + (cb >> 2)) * 64 + ((row & 15) | ((cb & 3) << 4));
                *(short8*)&Xs[unit * 8] = hi;
            }
        }
        __syncthreads();

        // K/V projection (port of qkv ak/av paths)
        f32x4 ak[4], av[4];
        #pragma unroll
        for (int i = 0; i < 4; i++) {
            ak[i] = (f32x4){0.f, 0.f, 0.f, 0.f};
            av[i] = (f32x4){0.f, 0.f, 0.f, 0.f};
        }
        #pragma unroll
        for (int ksi = 0; ksi < 4; ksi++) {
            #pragma unroll
            for (int rt = 0; rt < 4; rt++) {
                short8 ah = *(const short8*)&Xs[((rt * 4 + ksi) * 64 + lane) * 8];
                ak[rt] = __builtin_amdgcn_mfma_f32_16x16x32_bf16(ah, wkf[ksi], ak[rt], 0, 0, 0);
                av[rt] = __builtin_amdgcn_mfma_f32_16x16x32_bf16(ah, wvf[ksi], av[rt], 0, 0, 0);
            }
        }
        // scatter K to LDS frag layout (verbatim R4 kbase math, frag = rt*2+half)
        float vv[4][4];   // [r][rt]
        #pragma unroll
        for (int rt = 0; rt < 4; rt++) {
            #pragma unroll
            for (int r = 0; r < 4; r++) {
                float kv = fmaxf(ak[rt][r] + bkd, 0.f);
                vv[r][rt] = fmaxf(av[rt][r] + bvd, 0.f);
                KVb[0][(rt * 2 + half) * 512 + (quadk * 16 + quad * 4 + r) * 8 + jk] = f2bf(kv);
            }
        }
        // pack V to LDS frag layout (verbatim R4 vidx math, frag = dt*2+ckk)
        uint4 o0 = make_uint4(pack_bf16rn(vv[0][0], vv[0][1]), pack_bf16rn(vv[0][2], vv[0][3]),
                              pack_bf16rn(vv[1][0], vv[1][1]), pack_bf16rn(vv[1][2], vv[1][3]));
        uint4 o1 = make_uint4(pack_bf16rn(vv[2][0], vv[2][1]), pack_bf16rn(vv[2][2], vv[2][3]),
                              pack_bf16rn(vv[3][0], vv[3][1]), pack_bf16rn(vv[3][2], vv[3][3]));
        *(uint4*)&KVb[1][(dt * 2 + ckk) * 512 + (quadp * 16 + l16) * 8]      = o0;
        *(uint4*)&KVb[1][(dt * 2 + ckk) * 512 + (quadp * 16 + 16 + l16) * 8] = o1;
        __syncthreads();

        // ---- attn body (verbatim R9) ----
        short8 kf[4][2];
        #pragma unroll
        for (int kb = 0; kb < 4; kb++) {
            kf[kb][0] = *(const short8*)&KVb[0][(kb * 2 + 0) * 512 + lane * 8];
            kf[kb][1] = *(const short8*)&KVb[0][(kb * 2 + 1) * 512 + lane * 8];
        }
        f32x4 sc[2][4];
        #pragma unroll
        for (int s = 0; s < 2; s++) {
            #pragma unroll
            for (int kb = 0; kb < 4; kb++) {
                f32x4 z = (f32x4){0.f, 0.f, 0.f, 0.f};
                z = __builtin_amdgcn_mfma_f32_16x16x32_bf16(aq[s][0], kf[kb][0], z, 0, 0, 0);
                z = __builtin_amdgcn_mfma_f32_16x16x32_bf16(aq[s][1], kf[kb][1], z, 0, 0, 0);
                sc[s][kb] = z;
            }
        }
        short8 bvf[2][4];
        #pragma unroll
        for (int cb = 0; cb < 4; cb++) {
            bvf[0][cb] = *(const short8*)&KVb[1][(cb * 2 + 0) * 512 + lane * 8];
            bvf[1][cb] = *(const short8*)&KVb[1][(cb * 2 + 1) * 512 + lane * 8];
        }
        #pragma unroll
        for (int s = 0; s < 2; s++) {
            #pragma unroll
            for (int r = 0; r < 4; r++) {
                float p0 = __builtin_amdgcn_exp2f(sc[s][0][r]);
                float p1 = __builtin_amdgcn_exp2f(sc[s][1][r]);
                float p2 = __builtin_amdgcn_exp2f(sc[s][2][r]);
                float p3 = __builtin_amdgcn_exp2f(sc[s][3][r]);
                lsum[s][r] += (p0 + p1) + (p2 + p3);
                *(uint2*)&Pl[wave][s * 16 + quad * 4 + r][l16 * 4] =
                    make_uint2(pack_bf16rn(p0, p1), pack_bf16rn(p2, p3));
            }
        }
        #pragma unroll
        for (int ck = 0; ck < 2; ck++) {
            #pragma unroll
            for (int s = 0; s < 2; s++) {
                short8 ap = *(const short8*)&Pl[wave][s * 16 + l16][ck * 32 + quad * 8];
                #pragma unroll
                for (int cb = 0; cb < 4; cb++) {
                    O[s][cb] = __builtin_amdgcn_mfma_f32_16x16x32_bf16(ap, bvf[ck][cb], O[s][cb], 0, 0, 0);
                }
            }
        }
        __syncthreads();   // all waves done with KVb/Xs before next kt restages
    }

    // deferred row-sum reduction (lanes sharing a row: same quad, l16 0..15)
    #pragma unroll
    for (int s = 0; s < 2; s++)
        #pragma unroll
        for (int r = 0; r < 4; r++)
            #pragma unroll
            for (int off = 1; off < 16; off <<= 1)
                lsum[s][r] += __shfl_xor(lsum[s][r], off);

    // epilogue: out = O/l + q (q residual from Qs, same bits as before)
    #pragma unroll
    for (int s = 0; s < 2; s++) {
        #pragma unroll
        for (int r = 0; r < 4; r++) {
            float rl = 1.0f / lsum[s][r];
            int lrow = wave * 32 + s * 16 + quad * 4 + r;
            long nrow = (long)b * Nsz + qh * 128 + lrow;
            #pragma unroll
            for (int cb = 0; cb < 4; cb++) {
                int d2 = cb * 16 + l16;
                float qv = bf2f((unsigned short)Qs[lrow][d2]) * INV_SC;
                out[nrow * Dsz + d2] = O[s][cb][r] * rl + qv;
            }
        }
    }
}

extern "C" void kernel_launch(void* const* d_in, const int* in_sizes, int n_in,
                              void* d_out, int out_size, void* d_ws, size_t ws_size,
                              hipStream_t stream) {
    const float* x  = (const float*)d_in[0];
    const float* Wq = (const float*)d_in[1];
    const float* bq = (const float*)d_in[2];
    const float* Wk = (const float*)d_in[3];
    const float* bk = (const float*)d_in[4];
    const float* Wv = (const float*)d_in[5];
    const float* bv = (const float*)d_in[6];
    float* out = (float*)d_out;

    unsigned short* wfrag = (unsigned short*)d_ws;   // 64 KB W frags (only ws use)

    wprep_kernel<<<dim3(4), dim3(256), 0, stream>>>(Wq, Wk, Wv, wfrag);
    fused_kernel<<<dim3(512), dim3(256), 0, stream>>>(
        x, wfrag, bq, bk, bv, out);
}